// Round 4
// baseline (13768.105 us; speedup 1.0000x reference)
//
#include <hip/hip_runtime.h>

// B=8, C=256, H=W=64 -> N=4096, Cq=32. ALL I/O float32 (per reference dtypes).
// out = x + attn(x): q=wq x, k=wk x, v=wv x (1x1 conv), softmax over keys.
//
// v4 = v3 structure (two-pass softmax, zero cross-lane ops, barrier-separated)
// with float32 input/output instead of bf16 (rounds 0-2 misread fp32 as bf16).

#define CH   256
#define DQ   32
#define NSP  4096

// ---------------------------------------------------------------- proj ------
// grid (64, 5, ns); block 256; thread tile 4 rows x 4 n; weights read direct.
__global__ __launch_bounds__(256) void proj_kernel(
    const float* __restrict__ x,
    const float* __restrict__ wq, const float* __restrict__ bq,
    const float* __restrict__ wk, const float* __restrict__ bk,
    const float* __restrict__ wv, const float* __restrict__ bv,
    float* __restrict__ qT, float* __restrict__ kT, float* __restrict__ vB,
    int b0) {
  const int bz = blockIdx.z;            // local batch (workspace slot)
  const int bg = b0 + bz;               // global batch
  const int t  = threadIdx.x;
  const int r0 = blockIdx.y * 64 + ((t >> 6) << 4) + (((t >> 4) & 3) << 2);
  const int n  = blockIdx.x * 64 + ((t & 15) << 2);
  const float* xp = x + (size_t)bg * CH * NSP + n;

  const float* wrow[4];
  float acc[4][4];
#pragma unroll
  for (int rr = 0; rr < 4; ++rr) {
    int r = r0 + rr;
    float bias;
    if (r < 32)      { wrow[rr] = wq + r * CH;        bias = bq[r]; }
    else if (r < 64) { wrow[rr] = wk + (r - 32) * CH; bias = bk[r - 32]; }
    else             { wrow[rr] = wv + (r - 64) * CH; bias = bv[r - 64]; }
#pragma unroll
    for (int nn = 0; nn < 4; ++nn) acc[rr][nn] = bias;
  }

  for (int c4 = 0; c4 < CH; c4 += 4) {
    float4 xv[4];
#pragma unroll
    for (int cc = 0; cc < 4; ++cc)
      xv[cc] = *(const float4*)(xp + (size_t)(c4 + cc) * NSP);
#pragma unroll
    for (int rr = 0; rr < 4; ++rr) {
      float4 wr = *(const float4*)(wrow[rr] + c4);
      acc[rr][0] += wr.x * xv[0].x + wr.y * xv[1].x + wr.z * xv[2].x + wr.w * xv[3].x;
      acc[rr][1] += wr.x * xv[0].y + wr.y * xv[1].y + wr.z * xv[2].y + wr.w * xv[3].y;
      acc[rr][2] += wr.x * xv[0].z + wr.y * xv[1].z + wr.z * xv[2].z + wr.w * xv[3].z;
      acc[rr][3] += wr.x * xv[0].w + wr.y * xv[1].w + wr.z * xv[2].w + wr.w * xv[3].w;
    }
  }

#pragma unroll
  for (int rr = 0; rr < 4; ++rr) {
    int r = r0 + rr;
    float4 o = {acc[rr][0], acc[rr][1], acc[rr][2], acc[rr][3]};
    if (r < 32)      *(float4*)&qT[((size_t)bz * DQ + r) * NSP + n] = o;
    else if (r < 64) *(float4*)&kT[((size_t)bz * DQ + (r - 32)) * NSP + n] = o;
    else             *(float4*)&vB[((size_t)bz * CH + (r - 64)) * NSP + n] = o;
  }
}

// ---------------------------------------------------------------- stats -----
// grid (256, ns); block 256. Thread = (query ql = t>>4, key-segment kq = t&15);
// each thread scans 256 keys scalar-online; 16 partials combined in LDS.
// ml[(bz*NSP+i)*2] = m_i ; [..+1] = 1/l_i.
__global__ __launch_bounds__(256) void stats_kernel(
    const float* __restrict__ qT, const float* __restrict__ kT,
    float* __restrict__ ml) {
  const int bz = blockIdx.y;
  const int t  = threadIdx.x;
  const int ql = t >> 4, kq = t & 15;
  const int i  = blockIdx.x * 16 + ql;
  const float* qTb = qT + (size_t)bz * DQ * NSP;
  const float* kTb = kT + (size_t)bz * DQ * NSP;

  float qreg[DQ];
#pragma unroll
  for (int d = 0; d < DQ; ++d) qreg[d] = qTb[(size_t)d * NSP + i];

  float m = -3.0e38f, l = 0.0f;
  const float* kp = kTb + kq * 256;
  for (int jb = 0; jb < 64; ++jb) {
    float s0 = 0.f, s1 = 0.f, s2 = 0.f, s3 = 0.f;
#pragma unroll
    for (int d = 0; d < DQ; ++d) {
      float4 kk = *(const float4*)(kp + (size_t)d * NSP + jb * 4);
      s0 += qreg[d] * kk.x; s1 += qreg[d] * kk.y;
      s2 += qreg[d] * kk.z; s3 += qreg[d] * kk.w;
    }
    float smax = fmaxf(fmaxf(s0, s1), fmaxf(s2, s3));
    float mn   = fmaxf(m, smax);
    l = l * __expf(m - mn)
      + __expf(s0 - mn) + __expf(s1 - mn) + __expf(s2 - mn) + __expf(s3 - mn);
    m = mn;
  }

  __shared__ float ms[16][16], ls[16][16];
  ms[ql][kq] = m; ls[ql][kq] = l;
  __syncthreads();
  if (kq == 0) {
    float M = -3.0e38f;
#pragma unroll
    for (int u = 0; u < 16; ++u) M = fmaxf(M, ms[ql][u]);
    float L = 0.0f;
#pragma unroll
    for (int u = 0; u < 16; ++u) L += ls[ql][u] * __expf(ms[ql][u] - M);
    ml[((size_t)bz * NSP + i) * 2]     = M;
    ml[((size_t)bz * NSP + i) * 2 + 1] = 1.0f / L;
  }
}

// ---------------------------------------------------------------- output ----
// grid (128, ns); block 256 = 4 waves; 32 queries/block, all 256 channels.
// Per 32-key chunk, fully barrier-separated: stage kT/V -> S+P -> PV.
// S-phase: thread (rS = t>>3, j4 = (t&7)*4) computes 4 final p's.
// PV-phase: thread (w = t>>6, l = t&63): rows w*8..+7, channels l+64m.
__global__ __launch_bounds__(256) void out_kernel(
    const float* __restrict__ x,
    const float* __restrict__ qT, const float* __restrict__ kT,
    const float* __restrict__ vB, const float* __restrict__ ml,
    float* __restrict__ out, int b0) {
  __shared__ float ks_t[32][36];   // [key][d] +4 pad
  __shared__ float ps[32][36];     // [row][key] +4 pad
  __shared__ float vs[256 * 36];   // [c][key] f32, stride 36

  const int bz = blockIdx.y, bg = b0 + bz;
  const int i0 = blockIdx.x * 32;
  const int t  = threadIdx.x;
  const int w  = t >> 6, l = t & 63;
  const int rS = t >> 3;
  const int j4 = (t & 7) * 4;

  const float* qTb = qT + (size_t)bz * DQ * NSP;
  const float* kTb = kT + (size_t)bz * DQ * NSP;
  const float* vbase = vB + (size_t)bz * CH * NSP;

  float qreg[DQ];
#pragma unroll
  for (int d = 0; d < DQ; ++d) qreg[d] = qTb[(size_t)d * NSP + i0 + rS];
  const float mrow = ml[((size_t)bz * NSP + i0 + rS) * 2];
  const float linv = ml[((size_t)bz * NSP + i0 + rS) * 2 + 1];

  float acc[8][4];
#pragma unroll
  for (int r = 0; r < 8; ++r)
#pragma unroll
    for (int m2 = 0; m2 < 4; ++m2) acc[r][m2] = 0.0f;

  for (int j0 = 0; j0 < NSP; j0 += 32) {
    __syncthreads();                         // prev chunk's readers done
    {                                        // stage k^T: [key][d]
      int j = t >> 3, d4 = (t & 7) * 4;
#pragma unroll
      for (int u = 0; u < 4; ++u)
        ks_t[j][d4 + u] = kTb[(size_t)(d4 + u) * NSP + j0 + j];
    }
#pragma unroll
    for (int kk2 = 0; kk2 < 8; ++kk2) {      // stage V: 256c x 32k f32
      int u = t + kk2 * 256;                 // u in [0, 2048)
      int c = u >> 3, jg4 = (u & 7) * 4;
      float4 val = *(const float4*)(vbase + (size_t)c * NSP + j0 + jg4);
      *(float4*)&vs[c * 36 + jg4] = val;     // 36*4B row stride: 16B-aligned
    }
    __syncthreads();                         // staging visible

    {                                        // S + final P
      float s[4] = {0.f, 0.f, 0.f, 0.f};
#pragma unroll
      for (int dg = 0; dg < 8; ++dg) {
#pragma unroll
        for (int u = 0; u < 4; ++u) {
          float4 kk = *(const float4*)&ks_t[j4 + u][dg * 4];
          s[u] += qreg[dg * 4] * kk.x + qreg[dg * 4 + 1] * kk.y
                + qreg[dg * 4 + 2] * kk.z + qreg[dg * 4 + 3] * kk.w;
        }
      }
      float4 p4;
      p4.x = __expf(s[0] - mrow) * linv;
      p4.y = __expf(s[1] - mrow) * linv;
      p4.z = __expf(s[2] - mrow) * linv;
      p4.w = __expf(s[3] - mrow) * linv;
      *(float4*)&ps[rS][j4] = p4;
    }
    __syncthreads();                         // P visible to all

#pragma unroll
    for (int jg = 0; jg < 32; jg += 4) {     // PV
      float4 vv[4];
#pragma unroll
      for (int m2 = 0; m2 < 4; ++m2)
        vv[m2] = *(const float4*)&vs[(l + 64 * m2) * 36 + jg];
#pragma unroll
      for (int r = 0; r < 8; ++r) {
        float4 p4 = *(const float4*)&ps[w * 8 + r][jg];
#pragma unroll
        for (int m2 = 0; m2 < 4; ++m2)
          acc[r][m2] += p4.x * vv[m2].x + p4.y * vv[m2].y
                      + p4.z * vv[m2].z + p4.w * vv[m2].w;
      }
    }
  }

#pragma unroll
  for (int r = 0; r < 8; ++r) {              // epilogue (p already normalized)
    int i = i0 + w * 8 + r;
#pragma unroll
    for (int m2 = 0; m2 < 4; ++m2) {
      int c = l + 64 * m2;
      size_t idx = ((size_t)bg * CH + c) * NSP + i;
      out[idx] = acc[r][m2] + x[idx];
    }
  }
}

// ---------------------------------------------------------------- launch ----
extern "C" void kernel_launch(void* const* d_in, const int* in_sizes, int n_in,
                              void* d_out, int out_size, void* d_ws, size_t ws_size,
                              hipStream_t stream) {
  (void)in_sizes; (void)n_in; (void)out_size;
  const float* x  = (const float*)d_in[0];
  const float* wq = (const float*)d_in[1];
  const float* bq = (const float*)d_in[2];
  const float* wk = (const float*)d_in[3];
  const float* bk = (const float*)d_in[4];
  const float* wv = (const float*)d_in[5];
  const float* bv = (const float*)d_in[6];
  float* out = (float*)d_out;

  const size_t ML_B = (size_t)NSP * 2 * sizeof(float);   //   32 KiB / batch
  const size_t QK_B = (size_t)DQ * NSP * sizeof(float);  //  512 KiB / batch
  const size_t V_B  = (size_t)CH * NSP * sizeof(float);  // 4096 KiB / batch
  const size_t PER_B = ML_B + 2 * QK_B + V_B;            // ~5.06 MiB / batch

  int ns = 8;                       // batches staged concurrently
  while (ns > 1 && (size_t)ns * PER_B > ws_size) ns >>= 1;

  char* ws = (char*)d_ws;
  float* ml = (float*)ws;
  float* qT = (float*)(ws + (size_t)ns * ML_B);
  float* kT = (float*)(ws + (size_t)ns * (ML_B + QK_B));
  float* vB = (float*)(ws + (size_t)ns * (ML_B + 2 * QK_B));

  for (int b0 = 0; b0 < 8; b0 += ns) {
    proj_kernel<<<dim3(64, 5, ns), dim3(256), 0, stream>>>(
        x, wq, bq, wk, bk, wv, bv, qT, kT, vB, b0);
    stats_kernel<<<dim3(256, ns), dim3(256), 0, stream>>>(qT, kT, ml);
    out_kernel<<<dim3(128, ns), dim3(256), 0, stream>>>(
        x, qT, kT, vB, ml, out, b0);
  }
}

// Round 5
// 486.031 us; speedup vs baseline: 28.3277x; 28.3277x over previous
//
#include <hip/hip_runtime.h>

// B=8, C=256, H=W=64 -> N=4096, Cq=32. fp32 I/O.
// out = x + attn(x): q=wq x, k=wk x, v=wv x (1x1 conv), softmax over keys (no scale).
//
// v5: proj (fp32 VALU, bf16 outputs) + fused bf16-MFMA flash attention.
// MFMA 16x16x32_bf16 layouts (HW-verified): A[m=lane&15][k=quad*8+j],
// B[n=lane&15][k=quad*8+j], C/D: col=lane&15, row=quad*4+reg.

#define CH  256
#define DQ  32
#define NSP 4096

typedef short short8 __attribute__((ext_vector_type(8)));
typedef float float4v __attribute__((ext_vector_type(4)));

__device__ __forceinline__ unsigned short f2b(float f) {  // RNE f32->bf16
  unsigned int u = __float_as_uint(f);
  unsigned int r = u + 0x7fffu + ((u >> 16) & 1u);
  return (unsigned short)(r >> 16);
}
__device__ __forceinline__ short8 ld8(const unsigned short* p) {
  return *(const short8*)p;
}

// ---------------------------------------------------------------- proj ------
// grid (64, 5, ns); block 256; thread tile 4 rows x 4 n (v4-proven).
// Outputs: qb,kb bf16 [bz][i][32] ; vb bf16 [bz][c][N].
__global__ __launch_bounds__(256) void proj_kernel(
    const float* __restrict__ x,
    const float* __restrict__ wq, const float* __restrict__ bq,
    const float* __restrict__ wk, const float* __restrict__ bk,
    const float* __restrict__ wv, const float* __restrict__ bv,
    unsigned short* __restrict__ qb, unsigned short* __restrict__ kb,
    unsigned short* __restrict__ vb, int b0) {
  const int bz = blockIdx.z;
  const int bg = b0 + bz;
  const int t  = threadIdx.x;
  const int r0 = blockIdx.y * 64 + ((t >> 6) << 4) + (((t >> 4) & 3) << 2);
  const int n  = blockIdx.x * 64 + ((t & 15) << 2);
  const float* xp = x + (size_t)bg * CH * NSP + n;

  const float* wrow[4];
  float acc[4][4];
#pragma unroll
  for (int rr = 0; rr < 4; ++rr) {
    int r = r0 + rr;
    float bias;
    if (r < 32)      { wrow[rr] = wq + r * CH;        bias = bq[r]; }
    else if (r < 64) { wrow[rr] = wk + (r - 32) * CH; bias = bk[r - 32]; }
    else             { wrow[rr] = wv + (r - 64) * CH; bias = bv[r - 64]; }
#pragma unroll
    for (int nn = 0; nn < 4; ++nn) acc[rr][nn] = bias;
  }

  for (int c4 = 0; c4 < CH; c4 += 4) {
    float4 xv[4];
#pragma unroll
    for (int cc = 0; cc < 4; ++cc)
      xv[cc] = *(const float4*)(xp + (size_t)(c4 + cc) * NSP);
#pragma unroll
    for (int rr = 0; rr < 4; ++rr) {
      float4 wr = *(const float4*)(wrow[rr] + c4);
      acc[rr][0] += wr.x * xv[0].x + wr.y * xv[1].x + wr.z * xv[2].x + wr.w * xv[3].x;
      acc[rr][1] += wr.x * xv[0].y + wr.y * xv[1].y + wr.z * xv[2].y + wr.w * xv[3].y;
      acc[rr][2] += wr.x * xv[0].z + wr.y * xv[1].z + wr.z * xv[2].z + wr.w * xv[3].z;
      acc[rr][3] += wr.x * xv[0].w + wr.y * xv[1].w + wr.z * xv[2].w + wr.w * xv[3].w;
    }
  }

#pragma unroll
  for (int rr = 0; rr < 4; ++rr) {
    int r = r0 + rr;
    if (r < 32) {
#pragma unroll
      for (int nn = 0; nn < 4; ++nn)
        qb[((size_t)bz * NSP + n + nn) * DQ + r] = f2b(acc[rr][nn]);
    } else if (r < 64) {
#pragma unroll
      for (int nn = 0; nn < 4; ++nn)
        kb[((size_t)bz * NSP + n + nn) * DQ + (r - 32)] = f2b(acc[rr][nn]);
    } else {
      ushort4 o = {f2b(acc[rr][0]), f2b(acc[rr][1]), f2b(acc[rr][2]), f2b(acc[rr][3])};
      *(ushort4*)&vb[((size_t)bz * CH + (r - 64)) * NSP + n] = o;
    }
  }
}

// ---------------------------------------------------------------- attn ------
// grid (64*ns) flat; batch = blockIdx % ns (XCD-pins a batch's K/V in one L2).
// block 256 = 4 waves; 64 Q-rows/block; wave w owns softmax rows 16w..16w+15
// and PV channels [64w, 64w+64). Per 32-key chunk:
//   S (2 MFMAs, K direct from global/L2) -> wave-local online softmax ->
//   P,alpha through LDS -> barrier -> rescale acc, PV (16 MFMAs, V direct).
__global__ __launch_bounds__(256) void attn_kernel(
    const float* __restrict__ x,
    const unsigned short* __restrict__ qb, const unsigned short* __restrict__ kb,
    const unsigned short* __restrict__ vb,
    float* __restrict__ out, int b0, int ns) {
  __shared__ unsigned short ps[64][40];  // P bf16, row stride 40 (80B, 16B-aligned)
  __shared__ float als[64];              // per-row alpha (then l at epilogue)

  const int bl   = blockIdx.x % ns;
  const int bg   = b0 + bl;
  const int i0   = (blockIdx.x / ns) * 64;
  const int t    = threadIdx.x;
  const int w    = t >> 6;
  const int lane = t & 63;
  const int col  = lane & 15;
  const int quad = lane >> 4;

  const unsigned short* qbb = qb + (size_t)bl * NSP * DQ;
  const unsigned short* kbb = kb + (size_t)bl * NSP * DQ;
  const unsigned short* vbb = vb + (size_t)bl * CH * NSP;

  // Q A-fragment for this wave's 16 rows (persistent)
  const short8 qf = ld8(qbb + (size_t)(i0 + 16 * w + col) * DQ + quad * 8);

  float m_[4], l_[4];
#pragma unroll
  for (int r = 0; r < 4; ++r) { m_[r] = -3.0e38f; l_[r] = 0.0f; }

  float4v acc[4][4];  // [row-group][channel-tile]
#pragma unroll
  for (int rg = 0; rg < 4; ++rg)
#pragma unroll
    for (int ct = 0; ct < 4; ++ct)
      acc[rg][ct] = (float4v){0.f, 0.f, 0.f, 0.f};

  const float4v z4 = (float4v){0.f, 0.f, 0.f, 0.f};

  for (int j0 = 0; j0 < NSP; j0 += 32) {
    // ---- S = q . k^T for this wave's 16 rows x 32 keys ----
    const short8 kf0 = ld8(kbb + (size_t)(j0 + col) * DQ + quad * 8);
    const short8 kf1 = ld8(kbb + (size_t)(j0 + 16 + col) * DQ + quad * 8);
    float4v c0 = __builtin_amdgcn_mfma_f32_16x16x32_bf16(qf, kf0, z4, 0, 0, 0);
    float4v c1 = __builtin_amdgcn_mfma_f32_16x16x32_bf16(qf, kf1, z4, 0, 0, 0);

    // ---- online softmax (rows quad*4+reg; cols col / col+16) ----
    float alpha[4];
#pragma unroll
    for (int reg = 0; reg < 4; ++reg) {
      float s0 = c0[reg], s1 = c1[reg];
      float mx = fmaxf(s0, s1);
      mx = fmaxf(mx, __shfl_xor(mx, 1));
      mx = fmaxf(mx, __shfl_xor(mx, 2));
      mx = fmaxf(mx, __shfl_xor(mx, 4));
      mx = fmaxf(mx, __shfl_xor(mx, 8));
      float mn = fmaxf(m_[reg], mx);
      float p0 = __expf(s0 - mn), p1 = __expf(s1 - mn);
      float a  = __expf(m_[reg] - mn);
      float rs = p0 + p1;
      rs += __shfl_xor(rs, 1);
      rs += __shfl_xor(rs, 2);
      rs += __shfl_xor(rs, 4);
      rs += __shfl_xor(rs, 8);
      l_[reg] = l_[reg] * a + rs;
      m_[reg] = mn;
      alpha[reg] = a;
      int row = 16 * w + quad * 4 + reg;
      ps[row][col]      = f2b(p0);
      ps[row][col + 16] = f2b(p1);
    }
    if (col == 0) {
#pragma unroll
      for (int reg = 0; reg < 4; ++reg) als[16 * w + quad * 4 + reg] = alpha[reg];
    }
    __syncthreads();

    // ---- rescale acc, then PV over this wave's 64 channels ----
    float ar[4][4];
#pragma unroll
    for (int rg = 0; rg < 4; ++rg)
#pragma unroll
      for (int reg = 0; reg < 4; ++reg)
        ar[rg][reg] = als[rg * 16 + quad * 4 + reg];
#pragma unroll
    for (int rg = 0; rg < 4; ++rg)
#pragma unroll
      for (int ct = 0; ct < 4; ++ct)
#pragma unroll
        for (int reg = 0; reg < 4; ++reg)
          acc[rg][ct][reg] *= ar[rg][reg];

    short8 pf[4];
#pragma unroll
    for (int rg = 0; rg < 4; ++rg)
      pf[rg] = *(const short8*)&ps[rg * 16 + col][quad * 8];

#pragma unroll
    for (int ct = 0; ct < 4; ++ct) {
      int c = (w * 4 + ct) * 16 + col;
      const short8 vf = ld8(vbb + (size_t)c * NSP + j0 + quad * 8);
#pragma unroll
      for (int rg = 0; rg < 4; ++rg)
        acc[rg][ct] = __builtin_amdgcn_mfma_f32_16x16x32_bf16(pf[rg], vf, acc[rg][ct], 0, 0, 0);
    }
    __syncthreads();  // before next chunk overwrites ps/als
  }

  // ---- epilogue: publish l, normalize, residual, store ----
  if (col == 0) {
#pragma unroll
    for (int reg = 0; reg < 4; ++reg) als[16 * w + quad * 4 + reg] = l_[reg];
  }
  __syncthreads();

#pragma unroll
  for (int rg = 0; rg < 4; ++rg) {
    float linv[4];
#pragma unroll
    for (int reg = 0; reg < 4; ++reg)
      linv[reg] = 1.0f / als[rg * 16 + quad * 4 + reg];
#pragma unroll
    for (int ct = 0; ct < 4; ++ct) {
      int c  = (w * 4 + ct) * 16 + col;
      int ib = i0 + rg * 16 + quad * 4;
      size_t idx = ((size_t)bg * CH + c) * NSP + ib;
      float4 xr = *(const float4*)&x[idx];
      float4 o;
      o.x = acc[rg][ct][0] * linv[0] + xr.x;
      o.y = acc[rg][ct][1] * linv[1] + xr.y;
      o.z = acc[rg][ct][2] * linv[2] + xr.z;
      o.w = acc[rg][ct][3] * linv[3] + xr.w;
      *(float4*)&out[idx] = o;
    }
  }
}

// ---------------------------------------------------------------- launch ----
extern "C" void kernel_launch(void* const* d_in, const int* in_sizes, int n_in,
                              void* d_out, int out_size, void* d_ws, size_t ws_size,
                              hipStream_t stream) {
  (void)in_sizes; (void)n_in; (void)out_size;
  const float* x  = (const float*)d_in[0];
  const float* wq = (const float*)d_in[1];
  const float* bq = (const float*)d_in[2];
  const float* wk = (const float*)d_in[3];
  const float* bk = (const float*)d_in[4];
  const float* wv = (const float*)d_in[5];
  const float* bv = (const float*)d_in[6];
  float* out = (float*)d_out;

  const size_t QB_B = (size_t)NSP * DQ * sizeof(unsigned short);  // 256 KiB
  const size_t VB_B = (size_t)CH * NSP * sizeof(unsigned short);  //   2 MiB
  const size_t PER_B = 2 * QB_B + VB_B;                           // 2.5 MiB/batch

  int ns = 8;
  while (ns > 1 && (size_t)ns * PER_B > ws_size) ns >>= 1;

  char* ws = (char*)d_ws;
  unsigned short* qb = (unsigned short*)ws;
  unsigned short* kb = (unsigned short*)(ws + (size_t)ns * QB_B);
  unsigned short* vb = (unsigned short*)(ws + (size_t)ns * 2 * QB_B);

  for (int b0 = 0; b0 < 8; b0 += ns) {
    proj_kernel<<<dim3(64, 5, ns), dim3(256), 0, stream>>>(
        x, wq, bq, wk, bk, wv, bv, qb, kb, vb, b0);
    attn_kernel<<<dim3(64 * ns), dim3(256), 0, stream>>>(
        x, qb, kb, vb, out, b0, ns);
  }
}

// Round 7
// 434.410 us; speedup vs baseline: 31.6938x; 1.1188x over previous
//
#include <hip/hip_runtime.h>

// B=8, C=256, H=W=64 -> N=4096, Cq=32. fp32 I/O.
// out = x + attn(x): q=wq x, k=wk x, v=wv x (1x1 conv), softmax over keys (no scale).
//
// v6b: v6 with HIP-safe exp2/log2 builtins (__builtin_amdgcn_exp2f /
// __builtin_amdgcn_logf; v_exp_f32 = 2^x, v_log_f32 = log2 x).
// prep packs weights -> wall[320][256]; proj reads x ONCE per n-tile
// (320 rows/block); attn = fused two-pass softmax (pass0: per-lane online m,l,
// no per-chunk shuffles; pass1: p = exp2(s*log2e - moff), normalization folded
// into the exponent -> no rescale/alpha/l in the PV loop).
// MFMA 16x16x32_bf16 layouts (HW-verified): A[m=lane&15][k=quad*8+j],
// B[n=lane&15][k=quad*8+j], C/D: col=lane&15, row=quad*4+reg.

#define CH  256
#define DQ  32
#define NSP 4096
#define RWS 320

typedef short short8 __attribute__((ext_vector_type(8)));
typedef float float4v __attribute__((ext_vector_type(4)));

__device__ __forceinline__ unsigned short f2b(float f) {  // RNE f32->bf16
  unsigned int u = __float_as_uint(f);
  unsigned int r = u + 0x7fffu + ((u >> 16) & 1u);
  return (unsigned short)(r >> 16);
}
__device__ __forceinline__ short8 ld8(const unsigned short* p) {
  return *(const short8*)p;
}

// ---------------------------------------------------------------- prep ------
// wall[r][c] fp32 unified weight matrix (rows: 32 q, 32 k, 256 v), ball[r].
__global__ __launch_bounds__(256) void prep_kernel(
    const float* __restrict__ wq, const float* __restrict__ bq,
    const float* __restrict__ wk, const float* __restrict__ bk,
    const float* __restrict__ wv, const float* __restrict__ bv,
    float* __restrict__ wall, float* __restrict__ ball) {
  int r = blockIdx.x, c = threadIdx.x;
  float v;
  if (r < 32)       v = wq[r * CH + c];
  else if (r < 64)  v = wk[(r - 32) * CH + c];
  else              v = wv[(r - 64) * CH + c];
  wall[r * CH + c] = v;
  if (c == 0)
    ball[r] = (r < 32) ? bq[r] : (r < 64 ? bk[r - 32] : bv[r - 64]);
}

// ---------------------------------------------------------------- proj ------
// grid (64, ns); block 256. Each block: all 320 rows x 64 n (x read ONCE).
// Thread: 20 rows x 4 n. Outputs: qb,kb bf16 [bz][i][32]; vb bf16 [bz][c][N].
__global__ __launch_bounds__(256) void proj_kernel(
    const float* __restrict__ x,
    const float* __restrict__ wall, const float* __restrict__ ball,
    unsigned short* __restrict__ qb, unsigned short* __restrict__ kb,
    unsigned short* __restrict__ vb, int b0) {
  const int bz = blockIdx.y;
  const int bg = b0 + bz;
  const int t  = threadIdx.x;
  const int r0 = (t >> 4) * 20;             // 16 groups x 20 rows = 320
  const int n  = blockIdx.x * 64 + (t & 15) * 4;
  const float* xp = x + (size_t)bg * CH * NSP + n;

  float acc[20][4];
#pragma unroll
  for (int rr = 0; rr < 20; ++rr) {
    float bias = ball[r0 + rr];
#pragma unroll
    for (int nn = 0; nn < 4; ++nn) acc[rr][nn] = bias;
  }

#pragma unroll 1
  for (int c4 = 0; c4 < CH; c4 += 4) {
    float4 xv[4];
#pragma unroll
    for (int cc = 0; cc < 4; ++cc)
      xv[cc] = *(const float4*)(xp + (size_t)(c4 + cc) * NSP);
#pragma unroll
    for (int rr = 0; rr < 20; ++rr) {
      float4 wr = *(const float4*)(wall + (size_t)(r0 + rr) * CH + c4);
      acc[rr][0] += wr.x * xv[0].x + wr.y * xv[1].x + wr.z * xv[2].x + wr.w * xv[3].x;
      acc[rr][1] += wr.x * xv[0].y + wr.y * xv[1].y + wr.z * xv[2].y + wr.w * xv[3].y;
      acc[rr][2] += wr.x * xv[0].z + wr.y * xv[1].z + wr.z * xv[2].z + wr.w * xv[3].z;
      acc[rr][3] += wr.x * xv[0].w + wr.y * xv[1].w + wr.z * xv[2].w + wr.w * xv[3].w;
    }
  }

#pragma unroll
  for (int rr = 0; rr < 20; ++rr) {
    int r = r0 + rr;
    if (r < 32) {
#pragma unroll
      for (int nn = 0; nn < 4; ++nn)
        qb[((size_t)bz * NSP + n + nn) * DQ + r] = f2b(acc[rr][nn]);
    } else if (r < 64) {
#pragma unroll
      for (int nn = 0; nn < 4; ++nn)
        kb[((size_t)bz * NSP + n + nn) * DQ + (r - 32)] = f2b(acc[rr][nn]);
    } else {
      ushort4 o = {f2b(acc[rr][0]), f2b(acc[rr][1]), f2b(acc[rr][2]), f2b(acc[rr][3])};
      *(ushort4*)&vb[((size_t)bz * CH + (r - 64)) * NSP + n] = o;
    }
  }
}

// ---------------------------------------------------------------- attn ------
// grid (64*ns); batch = blockIdx % ns (pins each batch's K/V to one XCD L2).
// block 256 = 4 waves; 64 Q-rows/block; wave w: softmax rows 16w..16w+15,
// PV channels [64w, 64w+64).
// Pass 0: per-lane online (m,l) over all keys (no cross-lane per chunk),
//         4-step shuffle merge at end; moff = m*log2e + log2(l).
// Pass 1: S -> p = exp2(s*log2e - moff) (pre-normalized) -> LDS -> PV MFMAs.
__global__ __launch_bounds__(256) void attn_kernel(
    const float* __restrict__ x,
    const unsigned short* __restrict__ qb, const unsigned short* __restrict__ kb,
    const unsigned short* __restrict__ vb,
    float* __restrict__ out, int b0, int ns) {
  __shared__ unsigned short ps[64][40];  // P bf16, row stride 80 B (16B-aligned)

  const int bl   = blockIdx.x % ns;
  const int bg   = b0 + bl;
  const int i0   = (blockIdx.x / ns) * 64;
  const int t    = threadIdx.x;
  const int w    = t >> 6;
  const int lane = t & 63;
  const int col  = lane & 15;
  const int quad = lane >> 4;
  const float LOG2E = 1.4426950408889634f;

  const unsigned short* qbb = qb + (size_t)bl * NSP * DQ;
  const unsigned short* kbb = kb + (size_t)bl * NSP * DQ;
  const unsigned short* vbb = vb + (size_t)bl * CH * NSP;

  const short8 qf = ld8(qbb + (size_t)(i0 + 16 * w + col) * DQ + quad * 8);
  const float4v z4 = (float4v){0.f, 0.f, 0.f, 0.f};

  // ---------------- pass 0: per-lane online stats ----------------
  float m_[4], l_[4];
#pragma unroll
  for (int r = 0; r < 4; ++r) { m_[r] = -3.0e38f; l_[r] = 0.0f; }

  for (int j0 = 0; j0 < NSP; j0 += 32) {
    const short8 kf0 = ld8(kbb + (size_t)(j0 + col) * DQ + quad * 8);
    const short8 kf1 = ld8(kbb + (size_t)(j0 + 16 + col) * DQ + quad * 8);
    float4v c0 = __builtin_amdgcn_mfma_f32_16x16x32_bf16(qf, kf0, z4, 0, 0, 0);
    float4v c1 = __builtin_amdgcn_mfma_f32_16x16x32_bf16(qf, kf1, z4, 0, 0, 0);
#pragma unroll
    for (int reg = 0; reg < 4; ++reg) {
      float s0 = c0[reg], s1 = c1[reg];
      float mn = fmaxf(m_[reg], fmaxf(s0, s1));
      l_[reg] = l_[reg] * __expf(m_[reg] - mn)
              + __expf(s0 - mn) + __expf(s1 - mn);
      m_[reg] = mn;
    }
  }
  // merge across the 16 col-lanes (quad-local: masks 1,2,4,8)
#pragma unroll
  for (int reg = 0; reg < 4; ++reg) {
#pragma unroll
    for (int mask = 1; mask <= 8; mask <<= 1) {
      float mo = __shfl_xor(m_[reg], mask);
      float lo = __shfl_xor(l_[reg], mask);
      float mn = fmaxf(m_[reg], mo);
      l_[reg] = l_[reg] * __expf(m_[reg] - mn) + lo * __expf(mo - mn);
      m_[reg] = mn;
    }
  }
  float moff[4];
#pragma unroll
  for (int reg = 0; reg < 4; ++reg)
    moff[reg] = m_[reg] * LOG2E + __builtin_amdgcn_logf(l_[reg]);

  // ---------------- pass 1: P + PV ----------------
  float4v acc[4][4];  // [row-group][channel-tile]
#pragma unroll
  for (int rg = 0; rg < 4; ++rg)
#pragma unroll
    for (int ct = 0; ct < 4; ++ct) acc[rg][ct] = z4;

  for (int j0 = 0; j0 < NSP; j0 += 32) {
    const short8 kf0 = ld8(kbb + (size_t)(j0 + col) * DQ + quad * 8);
    const short8 kf1 = ld8(kbb + (size_t)(j0 + 16 + col) * DQ + quad * 8);
    float4v c0 = __builtin_amdgcn_mfma_f32_16x16x32_bf16(qf, kf0, z4, 0, 0, 0);
    float4v c1 = __builtin_amdgcn_mfma_f32_16x16x32_bf16(qf, kf1, z4, 0, 0, 0);
#pragma unroll
    for (int reg = 0; reg < 4; ++reg) {
      int row = 16 * w + quad * 4 + reg;
      float p0 = __builtin_amdgcn_exp2f(fmaf(c0[reg], LOG2E, -moff[reg]));
      float p1 = __builtin_amdgcn_exp2f(fmaf(c1[reg], LOG2E, -moff[reg]));
      ps[row][col]      = f2b(p0);
      ps[row][col + 16] = f2b(p1);
    }
    __syncthreads();

    short8 pf[4];
#pragma unroll
    for (int rg = 0; rg < 4; ++rg)
      pf[rg] = *(const short8*)&ps[rg * 16 + col][quad * 8];

#pragma unroll
    for (int ct = 0; ct < 4; ++ct) {
      int c = (w * 4 + ct) * 16 + col;
      const short8 vf = ld8(vbb + (size_t)c * NSP + j0 + quad * 8);
#pragma unroll
      for (int rg = 0; rg < 4; ++rg)
        acc[rg][ct] = __builtin_amdgcn_mfma_f32_16x16x32_bf16(pf[rg], vf, acc[rg][ct], 0, 0, 0);
    }
    __syncthreads();  // before next chunk overwrites ps
  }

  // ---------------- epilogue: residual + store (already normalized) --------
#pragma unroll
  for (int rg = 0; rg < 4; ++rg) {
#pragma unroll
    for (int ct = 0; ct < 4; ++ct) {
      int c  = (w * 4 + ct) * 16 + col;
      int ib = i0 + rg * 16 + quad * 4;
      size_t idx = ((size_t)bg * CH + c) * NSP + ib;
      float4 xr = *(const float4*)&x[idx];
      float4 o;
      o.x = acc[rg][ct][0] + xr.x;
      o.y = acc[rg][ct][1] + xr.y;
      o.z = acc[rg][ct][2] + xr.z;
      o.w = acc[rg][ct][3] + xr.w;
      *(float4*)&out[idx] = o;
    }
  }
}

// ---------------------------------------------------------------- launch ----
extern "C" void kernel_launch(void* const* d_in, const int* in_sizes, int n_in,
                              void* d_out, int out_size, void* d_ws, size_t ws_size,
                              hipStream_t stream) {
  (void)in_sizes; (void)n_in; (void)out_size;
  const float* x  = (const float*)d_in[0];
  const float* wq = (const float*)d_in[1];
  const float* bq = (const float*)d_in[2];
  const float* wk = (const float*)d_in[3];
  const float* bk = (const float*)d_in[4];
  const float* wv = (const float*)d_in[5];
  const float* bv = (const float*)d_in[6];
  float* out = (float*)d_out;

  const size_t WALL_B = (size_t)RWS * CH * sizeof(float) + 4096;  // wall+ball
  const size_t QB_B = (size_t)NSP * DQ * sizeof(unsigned short);  // 256 KiB
  const size_t VB_B = (size_t)CH * NSP * sizeof(unsigned short);  //   2 MiB
  const size_t PER_B = 2 * QB_B + VB_B;                           // 2.5 MiB/batch

  int ns = 8;
  while (ns > 1 && WALL_B + (size_t)ns * PER_B > ws_size) ns >>= 1;

  char* ws = (char*)d_ws;
  float* wall = (float*)ws;
  float* ball = (float*)(ws + (size_t)RWS * CH * sizeof(float));
  char* qkv = ws + WALL_B;
  unsigned short* qb = (unsigned short*)qkv;
  unsigned short* kb = (unsigned short*)(qkv + (size_t)ns * QB_B);
  unsigned short* vb = (unsigned short*)(qkv + (size_t)ns * 2 * QB_B);

  prep_kernel<<<dim3(RWS), dim3(256), 0, stream>>>(wq, bq, wk, bk, wv, bv, wall, ball);
  for (int b0 = 0; b0 < 8; b0 += ns) {
    proj_kernel<<<dim3(64, ns), dim3(256), 0, stream>>>(
        x, wall, ball, qb, kb, vb, b0);
    attn_kernel<<<dim3(64 * ns), dim3(256), 0, stream>>>(
        x, qb, kb, vb, out, b0, ns);
  }
}